// Round 1
// baseline (262.570 us; speedup 1.0000x reference)
//
#include <hip/hip_runtime.h>

#define NN 50000
#define EE 400000
#define CIN 16
#define COUT 32

// ---- workspace layout (bytes) ----
#define OFF_AGG   0                        // float agg[NN*COUT]
#define OFF_DEG   (NN*COUT*4)              // int   degi[NN]
#define OFF_HIST  (OFF_DEG + NN*4)         // int   hist[64]
#define OFF_CUR   (OFF_HIST + 256)         // int   cursors[64]
#define OFF_SUM   (OFF_CUR + 256)          // float gsum[32]
#define OFF_SUMSQ (OFF_SUM + 128)          // float gsumsq[32]
#define ZERO_BYTES (OFF_SUMSQ + 128)
#define OFF_OFFS  ZERO_BYTES               // int offsets[65] (pad 512)
#define OFF_SORT  (OFF_OFFS + 512)         // int sorted[EE]

__device__ __forceinline__ void cell_of(float a0, float a1, float a2,
                                        int& l0, int& l1, int& l2,
                                        float& f0, float& f1, float& f2) {
  float v0 = a0 * 4.0f, v1 = a1 * 4.0f, v2 = a2 * 4.0f;
  l0 = min(max((int)v0, 0), 3);
  l1 = min(max((int)v1, 0), 3);
  l2 = min(max((int)v2, 0), 3);
  f0 = v0 - (float)l0; f1 = v1 - (float)l1; f2 = v2 - (float)l2;
}

// K1: per-cell histogram + in-degree
__global__ void k_hist(const float* __restrict__ attr, const int* __restrict__ edst,
                       int* __restrict__ hist, int* __restrict__ degi) {
  __shared__ int lh[64];
  if (threadIdx.x < 64) lh[threadIdx.x] = 0;
  __syncthreads();
  for (int e = blockIdx.x * blockDim.x + threadIdx.x; e < EE; e += gridDim.x * blockDim.x) {
    int l0, l1, l2; float f0, f1, f2;
    cell_of(attr[e*3], attr[e*3+1], attr[e*3+2], l0, l1, l2, f0, f1, f2);
    atomicAdd(&lh[l0 | (l1 << 2) | (l2 << 4)], 1);
    atomicAdd(&degi[edst[e]], 1);
  }
  __syncthreads();
  if (threadIdx.x < 64 && lh[threadIdx.x]) atomicAdd(&hist[threadIdx.x], lh[threadIdx.x]);
}

// K2: serial prefix over 64 bins
__global__ void k_prefix(const int* __restrict__ hist, int* __restrict__ offsets) {
  if (threadIdx.x == 0) {
    int r = 0;
    for (int c = 0; c < 64; ++c) { offsets[c] = r; r += hist[c]; }
    offsets[64] = r;
  }
}

// K3: two-level scatter into cell buckets
__global__ void k_scatter(const float* __restrict__ attr, const int* __restrict__ offsets,
                          int* __restrict__ cursors, int* __restrict__ sorted) {
  __shared__ int lcnt[64], lbase[64], lcur[64];
  int tid = threadIdx.x;
  if (tid < 64) { lcnt[tid] = 0; lcur[tid] = 0; }
  __syncthreads();
  int per = (EE + gridDim.x - 1) / gridDim.x;
  int b0 = blockIdx.x * per;
  int b1 = min(b0 + per, EE);
  for (int e = b0 + tid; e < b1; e += blockDim.x) {
    int l0, l1, l2; float f0, f1, f2;
    cell_of(attr[e*3], attr[e*3+1], attr[e*3+2], l0, l1, l2, f0, f1, f2);
    atomicAdd(&lcnt[l0 | (l1 << 2) | (l2 << 4)], 1);
  }
  __syncthreads();
  if (tid < 64 && lcnt[tid]) lbase[tid] = offsets[tid] + atomicAdd(&cursors[tid], lcnt[tid]);
  __syncthreads();
  for (int e = b0 + tid; e < b1; e += blockDim.x) {
    int l0, l1, l2; float f0, f1, f2;
    cell_of(attr[e*3], attr[e*3+1], attr[e*3+2], l0, l1, l2, f0, f1, f2);
    int c = l0 | (l1 << 2) | (l2 << 4);
    int p = atomicAdd(&lcur[c], 1);
    sorted[lbase[c] + p] = e;
  }
}

// K4: main edge kernel. Wave = 64 lanes; lane = (o in 0..31, half hh in 0..1).
// Each wave processes a contiguous chunk of the cell-sorted edge list, holding
// the 8 corner matrices of the current cell in registers: lane(o,hh) keeps
// W[combo=4*hh+s4][i][o] for s4 in 0..3, i in 0..15  -> 64 VGPRs.
__global__ __launch_bounds__(256) void k_edge(
    const float* __restrict__ x, const int* __restrict__ esrc, const int* __restrict__ edst,
    const float* __restrict__ attr, const float* __restrict__ weight,
    const int* __restrict__ sorted, float* __restrict__ agg, int nwaves) {
  int gwave = (blockIdx.x * blockDim.x + threadIdx.x) >> 6;
  int lane = threadIdx.x & 63;
  int o = lane & 31;
  int hh = lane >> 5;
  int per = (EE + nwaves - 1) / nwaves;
  int p0 = gwave * per;
  int p1 = min(p0 + per, EE);

  float W[4][16];
  int cur = -1;

  for (int p = p0; p < p1; ++p) {
    int e = __builtin_amdgcn_readfirstlane(sorted[p]);
    int l0, l1, l2; float f0, f1, f2;
    cell_of(attr[e*3], attr[e*3+1], attr[e*3+2], l0, l1, l2, f0, f1, f2);
    int cell = __builtin_amdgcn_readfirstlane(l0 | (l1 << 2) | (l2 << 4));

    if (cell != cur) {
      cur = cell;
      int c0 = cell & 3, c1 = (cell >> 2) & 3, c2 = cell >> 4;
#pragma unroll
      for (int s4 = 0; s4 < 4; ++s4) {
        int c = hh * 4 + s4;
        int wi = (c0 + (c & 1)) + 5 * (c1 + ((c >> 1) & 1)) + 25 * (c2 + ((c >> 2) & 1));
        const float* wp = weight + wi * (CIN * COUT) + o;
#pragma unroll
        for (int i = 0; i < CIN; ++i) W[s4][i] = wp[i * COUT];
      }
    }

    int src = __builtin_amdgcn_readfirstlane(esrc[e]);
    int dst = __builtin_amdgcn_readfirstlane(edst[e]);
    const float* xp = x + src * CIN;
    float xs[CIN];
#pragma unroll
    for (int i = 0; i < CIN; ++i) xs[i] = xp[i];

    float acc = 0.0f;
#pragma unroll
    for (int s4 = 0; s4 < 4; ++s4) {
      float bw = ((s4 & 1)      ? f0 : 1.0f - f0)
               * (((s4 >> 1) & 1) ? f1 : 1.0f - f1)
               * (hh             ? f2 : 1.0f - f2);
      float m = 0.0f;
#pragma unroll
      for (int i = 0; i < CIN; ++i) m = fmaf(xs[i], W[s4][i], m);
      acc = fmaf(bw, m, acc);
    }
    acc += __shfl_xor(acc, 32);
    if (hh == 0) atomicAdd(&agg[dst * COUT + o], acc);
  }
}

// K5: node kernel: mean-agg + x@root + bias, ELU, write h to out, BN partial sums
__global__ __launch_bounds__(1024) void k_node(
    const float* __restrict__ x, const float* __restrict__ agg, const int* __restrict__ degi,
    const float* __restrict__ root, const float* __restrict__ bias,
    float* __restrict__ hout, float* __restrict__ gsum, float* __restrict__ gsumsq) {
  __shared__ float sred[2][16][32];
  int tid = threadIdx.x;
  int o = tid & 31;
  int nl = tid >> 5;                 // node within block, 0..31
  int n = blockIdx.x * 32 + nl;
  float s1 = 0.0f, s2 = 0.0f;
  if (n < NN) {
    float a = agg[n * COUT + o] / fmaxf((float)degi[n], 1.0f);
    const float* xp = x + n * CIN;
    float r = 0.0f;
#pragma unroll
    for (int i = 0; i < CIN; ++i) r = fmaf(xp[i], root[i * COUT + o], r);
    float hv = a + r + bias[o];
    hv = hv > 0.0f ? hv : expm1f(hv);
    hout[n * COUT + o] = hv;
    s1 = hv; s2 = hv * hv;
  }
  s1 += __shfl_xor(s1, 32);
  s2 += __shfl_xor(s2, 32);
  int w = tid >> 6;                  // wave 0..15
  if ((tid & 63) < 32) { sred[0][w][o] = s1; sred[1][w][o] = s2; }
  __syncthreads();
  if (tid < 32) {
    float t1 = 0.0f, t2 = 0.0f;
#pragma unroll
    for (int w2 = 0; w2 < 16; ++w2) { t1 += sred[0][w2][o]; t2 += sred[1][w2][o]; }
    atomicAdd(&gsum[o], t1);
    atomicAdd(&gsumsq[o], t2);
  }
}

// K6: finalize BatchNorm in-place on out
__global__ void k_bn(float* __restrict__ out, const float* __restrict__ gsum,
                     const float* __restrict__ gsumsq, const float* __restrict__ gamma,
                     const float* __restrict__ beta) {
  int idx = blockIdx.x * blockDim.x + threadIdx.x;
  if (idx >= NN * COUT) return;
  int o = idx & 31;
  float m = gsum[o] * (1.0f / NN);
  float var = gsumsq[o] * (1.0f / NN) - m * m;
  float inv = rsqrtf(var + 1e-5f);
  out[idx] = (out[idx] - m) * inv * gamma[o] + beta[o];
}

extern "C" void kernel_launch(void* const* d_in, const int* in_sizes, int n_in,
                              void* d_out, int out_size, void* d_ws, size_t ws_size,
                              hipStream_t stream) {
  const float* x      = (const float*)d_in[0];
  const int*   ei     = (const int*)d_in[1];
  const float* attr   = (const float*)d_in[2];
  const float* weight = (const float*)d_in[3];
  const float* root   = (const float*)d_in[4];
  const float* bias   = (const float*)d_in[5];
  const float* gamma  = (const float*)d_in[6];
  const float* beta   = (const float*)d_in[7];
  float* out = (float*)d_out;
  char* ws = (char*)d_ws;

  float* agg     = (float*)(ws + OFF_AGG);
  int*   degi    = (int*)(ws + OFF_DEG);
  int*   hist    = (int*)(ws + OFF_HIST);
  int*   cursors = (int*)(ws + OFF_CUR);
  float* gsum    = (float*)(ws + OFF_SUM);
  float* gsumsq  = (float*)(ws + OFF_SUMSQ);
  int*   offsets = (int*)(ws + OFF_OFFS);
  int*   sorted  = (int*)(ws + OFF_SORT);
  const int* esrc = ei;
  const int* edst = ei + EE;

  hipMemsetAsync(ws, 0, ZERO_BYTES, stream);
  k_hist<<<512, 256, 0, stream>>>(attr, edst, hist, degi);
  k_prefix<<<1, 64, 0, stream>>>(hist, offsets);
  k_scatter<<<512, 256, 0, stream>>>(attr, offsets, cursors, sorted);
  const int NB4 = 1536;
  k_edge<<<NB4, 256, 0, stream>>>(x, esrc, edst, attr, weight, sorted, agg, NB4 * 4);
  k_node<<<(NN + 31) / 32, 1024, 0, stream>>>(x, agg, degi, root, bias, out, gsum, gsumsq);
  k_bn<<<(NN * COUT) / 256, 256, 0, stream>>>(out, gsum, gsumsq, gamma, beta);
}

// Round 2
// 220.521 us; speedup vs baseline: 1.1907x; 1.1907x over previous
//
#include <hip/hip_runtime.h>

#define NN 50000
#define EE 400000
#define CIN 16
#define COUT 32

// ---- workspace layout (bytes) ----
#define OFF_AGG   0                        // float agg[NN*COUT]
#define OFF_DEG   (NN*COUT*4)              // int   degi[NN]
#define OFF_HIST  (OFF_DEG + NN*4)         // int   hist[64]
#define OFF_CUR   (OFF_HIST + 256)         // int   cursors[64]
#define OFF_SUM   (OFF_CUR + 256)          // float gsum[32]
#define OFF_SUMSQ (OFF_SUM + 128)          // float gsumsq[32]
#define ZERO_BYTES (OFF_SUMSQ + 128)
#define OFF_OFFS  ZERO_BYTES               // int offsets[65] (pad 512)
#define OFF_SORT  (OFF_OFFS + 512)         // int sorted[EE]

typedef float f16v __attribute__((ext_vector_type(16)));

__device__ __forceinline__ void cell_of(float a0, float a1, float a2,
                                        int& l0, int& l1, int& l2,
                                        float& f0, float& f1, float& f2) {
  float v0 = a0 * 4.0f, v1 = a1 * 4.0f, v2 = a2 * 4.0f;
  l0 = min(max((int)v0, 0), 3);
  l1 = min(max((int)v1, 0), 3);
  l2 = min(max((int)v2, 0), 3);
  f0 = v0 - (float)l0; f1 = v1 - (float)l1; f2 = v2 - (float)l2;
}

// K1: per-cell histogram + in-degree
__global__ void k_hist(const float* __restrict__ attr, const int* __restrict__ edst,
                       int* __restrict__ hist, int* __restrict__ degi) {
  __shared__ int lh[64];
  if (threadIdx.x < 64) lh[threadIdx.x] = 0;
  __syncthreads();
  for (int e = blockIdx.x * blockDim.x + threadIdx.x; e < EE; e += gridDim.x * blockDim.x) {
    int l0, l1, l2; float f0, f1, f2;
    cell_of(attr[e*3], attr[e*3+1], attr[e*3+2], l0, l1, l2, f0, f1, f2);
    atomicAdd(&lh[l0 | (l1 << 2) | (l2 << 4)], 1);
    atomicAdd(&degi[edst[e]], 1);
  }
  __syncthreads();
  if (threadIdx.x < 64 && lh[threadIdx.x]) atomicAdd(&hist[threadIdx.x], lh[threadIdx.x]);
}

// K2: serial prefix over 64 bins
__global__ void k_prefix(const int* __restrict__ hist, int* __restrict__ offsets) {
  if (threadIdx.x == 0) {
    int r = 0;
    for (int c = 0; c < 64; ++c) { offsets[c] = r; r += hist[c]; }
    offsets[64] = r;
  }
}

// K3: two-level scatter into cell buckets
__global__ void k_scatter(const float* __restrict__ attr, const int* __restrict__ offsets,
                          int* __restrict__ cursors, int* __restrict__ sorted) {
  __shared__ int lcnt[64], lbase[64], lcur[64];
  int tid = threadIdx.x;
  if (tid < 64) { lcnt[tid] = 0; lcur[tid] = 0; }
  __syncthreads();
  int per = (EE + gridDim.x - 1) / gridDim.x;
  int b0 = blockIdx.x * per;
  int b1 = min(b0 + per, EE);
  for (int e = b0 + tid; e < b1; e += blockDim.x) {
    int l0, l1, l2; float f0, f1, f2;
    cell_of(attr[e*3], attr[e*3+1], attr[e*3+2], l0, l1, l2, f0, f1, f2);
    atomicAdd(&lcnt[l0 | (l1 << 2) | (l2 << 4)], 1);
  }
  __syncthreads();
  if (tid < 64 && lcnt[tid]) lbase[tid] = offsets[tid] + atomicAdd(&cursors[tid], lcnt[tid]);
  __syncthreads();
  for (int e = b0 + tid; e < b1; e += blockDim.x) {
    int l0, l1, l2; float f0, f1, f2;
    cell_of(attr[e*3], attr[e*3+1], attr[e*3+2], l0, l1, l2, f0, f1, f2);
    int c = l0 | (l1 << 2) | (l2 << 4);
    int p = atomicAdd(&lcur[c], 1);
    sorted[lbase[c] + p] = e;
  }
}

// K4: main edge kernel. Wave = 64 lanes; lane = (o in 0..31, half hh in 0..1).
// Two-level loop: outer over cells (W held in 4x ext_vector<16> = 64 VGPRs,
// all element indices compile-time), inner clean per-edge loop bounded by
// offsets[cell+1] -- no conditional W-fill in the hot path.
__global__ __launch_bounds__(256) void k_edge(
    const float* __restrict__ x, const int* __restrict__ esrc, const int* __restrict__ edst,
    const float* __restrict__ attr, const float* __restrict__ weight,
    const int* __restrict__ sorted, const int* __restrict__ offsets,
    float* __restrict__ agg, int nwaves) {
  int gwave = (blockIdx.x * blockDim.x + threadIdx.x) >> 6;
  int lane = threadIdx.x & 63;
  int o = lane & 31;
  int hh = lane >> 5;
  int per = (EE + nwaves - 1) / nwaves;
  int p0 = gwave * per;
  int p1 = min(p0 + per, EE);

  f16v W0, W1, W2, W3;

#define LOADW(Wv, S4) do {                                                    \
    int c_ = hh * 4 + (S4);                                                   \
    int wi_ = (c0 + (c_ & 1)) + 5 * (c1 + ((c_ >> 1) & 1)) + 25 * (c2 + (c_ >> 2)); \
    const float* wp_ = weight + wi_ * (CIN * COUT) + o;                       \
    _Pragma("unroll")                                                         \
    for (int i_ = 0; i_ < 16; ++i_) Wv[i_] = wp_[i_ * 32];                    \
  } while (0)

  int p = p0;
  while (p < p1) {
    // determine current cell from first edge of the run
    int e0 = __builtin_amdgcn_readfirstlane(sorted[p]);
    int l0, l1, l2; float t0, t1, t2;
    cell_of(attr[e0*3], attr[e0*3+1], attr[e0*3+2], l0, l1, l2, t0, t1, t2);
    int cell = __builtin_amdgcn_readfirstlane(l0 | (l1 << 2) | (l2 << 4));
    int c0 = cell & 3, c1 = (cell >> 2) & 3, c2 = cell >> 4;
    LOADW(W0, 0); LOADW(W1, 1); LOADW(W2, 2); LOADW(W3, 3);
    int pe = min(p1, offsets[cell + 1]);

    for (; p < pe; ++p) {
      int e = __builtin_amdgcn_readfirstlane(sorted[p]);
      float v0 = attr[e*3] * 4.0f, v1 = attr[e*3+1] * 4.0f, v2 = attr[e*3+2] * 4.0f;
      float f0 = v0 - (float)c0, f1 = v1 - (float)c1, f2 = v2 - (float)c2;
      int src = __builtin_amdgcn_readfirstlane(esrc[e]);
      int dst = __builtin_amdgcn_readfirstlane(edst[e]);
      const float* xp = x + src * CIN;
      float m0 = 0.0f, m1 = 0.0f, m2 = 0.0f, m3 = 0.0f;
#pragma unroll
      for (int i = 0; i < CIN; ++i) {
        float xi = xp[i];
        m0 = fmaf(xi, W0[i], m0);
        m1 = fmaf(xi, W1[i], m1);
        m2 = fmaf(xi, W2[i], m2);
        m3 = fmaf(xi, W3[i], m3);
      }
      float g0 = 1.0f - f0, g1 = 1.0f - f1;
      float bz = hh ? f2 : 1.0f - f2;
      float acc = (g0 * g1) * m0;
      acc = fmaf(f0 * g1, m1, acc);
      acc = fmaf(g0 * f1, m2, acc);
      acc = fmaf(f0 * f1, m3, acc);
      acc *= bz;
      acc += __shfl_xor(acc, 32);
      if (hh == 0) atomicAdd(&agg[dst * COUT + o], acc);
    }
  }
#undef LOADW
}

// K5: node kernel: mean-agg + x@root + bias, ELU, write h to out, BN partial sums
__global__ __launch_bounds__(1024) void k_node(
    const float* __restrict__ x, const float* __restrict__ agg, const int* __restrict__ degi,
    const float* __restrict__ root, const float* __restrict__ bias,
    float* __restrict__ hout, float* __restrict__ gsum, float* __restrict__ gsumsq) {
  __shared__ float sred[2][16][32];
  int tid = threadIdx.x;
  int o = tid & 31;
  int nl = tid >> 5;                 // node within block, 0..31
  int n = blockIdx.x * 32 + nl;
  float s1 = 0.0f, s2 = 0.0f;
  if (n < NN) {
    float a = agg[n * COUT + o] / fmaxf((float)degi[n], 1.0f);
    const float* xp = x + n * CIN;
    float r = 0.0f;
#pragma unroll
    for (int i = 0; i < CIN; ++i) r = fmaf(xp[i], root[i * COUT + o], r);
    float hv = a + r + bias[o];
    hv = hv > 0.0f ? hv : expm1f(hv);
    hout[n * COUT + o] = hv;
    s1 = hv; s2 = hv * hv;
  }
  s1 += __shfl_xor(s1, 32);
  s2 += __shfl_xor(s2, 32);
  int w = tid >> 6;                  // wave 0..15
  if ((tid & 63) < 32) { sred[0][w][o] = s1; sred[1][w][o] = s2; }
  __syncthreads();
  if (tid < 32) {
    float t1 = 0.0f, t2 = 0.0f;
#pragma unroll
    for (int w2 = 0; w2 < 16; ++w2) { t1 += sred[0][w2][o]; t2 += sred[1][w2][o]; }
    atomicAdd(&gsum[o], t1);
    atomicAdd(&gsumsq[o], t2);
  }
}

// K6: finalize BatchNorm in-place on out
__global__ void k_bn(float* __restrict__ out, const float* __restrict__ gsum,
                     const float* __restrict__ gsumsq, const float* __restrict__ gamma,
                     const float* __restrict__ beta) {
  int idx = blockIdx.x * blockDim.x + threadIdx.x;
  if (idx >= NN * COUT) return;
  int o = idx & 31;
  float m = gsum[o] * (1.0f / NN);
  float var = gsumsq[o] * (1.0f / NN) - m * m;
  float inv = rsqrtf(var + 1e-5f);
  out[idx] = (out[idx] - m) * inv * gamma[o] + beta[o];
}

extern "C" void kernel_launch(void* const* d_in, const int* in_sizes, int n_in,
                              void* d_out, int out_size, void* d_ws, size_t ws_size,
                              hipStream_t stream) {
  const float* x      = (const float*)d_in[0];
  const int*   ei     = (const int*)d_in[1];
  const float* attr   = (const float*)d_in[2];
  const float* weight = (const float*)d_in[3];
  const float* root   = (const float*)d_in[4];
  const float* bias   = (const float*)d_in[5];
  const float* gamma  = (const float*)d_in[6];
  const float* beta   = (const float*)d_in[7];
  float* out = (float*)d_out;
  char* ws = (char*)d_ws;

  float* agg     = (float*)(ws + OFF_AGG);
  int*   degi    = (int*)(ws + OFF_DEG);
  int*   hist    = (int*)(ws + OFF_HIST);
  int*   cursors = (int*)(ws + OFF_CUR);
  float* gsum    = (float*)(ws + OFF_SUM);
  float* gsumsq  = (float*)(ws + OFF_SUMSQ);
  int*   offsets = (int*)(ws + OFF_OFFS);
  int*   sorted  = (int*)(ws + OFF_SORT);
  const int* esrc = ei;
  const int* edst = ei + EE;

  hipMemsetAsync(ws, 0, ZERO_BYTES, stream);
  k_hist<<<512, 256, 0, stream>>>(attr, edst, hist, degi);
  k_prefix<<<1, 64, 0, stream>>>(hist, offsets);
  k_scatter<<<512, 256, 0, stream>>>(attr, offsets, cursors, sorted);
  const int NB4 = 1024;  // 4096 waves = one full-occupancy pass at ~4 waves/SIMD
  k_edge<<<NB4, 256, 0, stream>>>(x, esrc, edst, attr, weight, sorted, offsets, agg, NB4 * 4);
  k_node<<<(NN + 31) / 32, 1024, 0, stream>>>(x, agg, degi, root, bias, out, gsum, gsumsq);
  k_bn<<<(NN * COUT) / 256, 256, 0, stream>>>(out, gsum, gsumsq, gamma, beta);
}

// Round 3
// 220.375 us; speedup vs baseline: 1.1915x; 1.0007x over previous
//
#include <hip/hip_runtime.h>

#define NN 50000
#define EE 400000
#define CIN 16
#define COUT 32

// ---- workspace layout (bytes) ----
#define OFF_AGG   0                        // float agg[NN*COUT]
#define OFF_DEG   (NN*COUT*4)              // int   degi[NN]
#define OFF_HIST  (OFF_DEG + NN*4)         // int   hist[64]
#define OFF_CUR   (OFF_HIST + 256)         // int   cursors[64]
#define OFF_SUM   (OFF_CUR + 256)          // float gsum[32]
#define OFF_SUMSQ (OFF_SUM + 128)          // float gsumsq[32]
#define ZERO_BYTES (OFF_SUMSQ + 128)
#define OFF_OFFS  ZERO_BYTES               // int offsets[65] (pad 512)
#define OFF_SORT  (OFF_OFFS + 512)         // int sorted[EE]

typedef float f16v __attribute__((ext_vector_type(16)));

__device__ __forceinline__ void cell_of(float a0, float a1, float a2,
                                        int& l0, int& l1, int& l2,
                                        float& f0, float& f1, float& f2) {
  float v0 = a0 * 4.0f, v1 = a1 * 4.0f, v2 = a2 * 4.0f;
  l0 = min(max((int)v0, 0), 3);
  l1 = min(max((int)v1, 0), 3);
  l2 = min(max((int)v2, 0), 3);
  f0 = v0 - (float)l0; f1 = v1 - (float)l1; f2 = v2 - (float)l2;
}

// K1: per-cell histogram + in-degree
__global__ void k_hist(const float* __restrict__ attr, const int* __restrict__ edst,
                       int* __restrict__ hist, int* __restrict__ degi) {
  __shared__ int lh[64];
  if (threadIdx.x < 64) lh[threadIdx.x] = 0;
  __syncthreads();
  for (int e = blockIdx.x * blockDim.x + threadIdx.x; e < EE; e += gridDim.x * blockDim.x) {
    int l0, l1, l2; float f0, f1, f2;
    cell_of(attr[e*3], attr[e*3+1], attr[e*3+2], l0, l1, l2, f0, f1, f2);
    atomicAdd(&lh[l0 | (l1 << 2) | (l2 << 4)], 1);
    atomicAdd(&degi[edst[e]], 1);
  }
  __syncthreads();
  if (threadIdx.x < 64 && lh[threadIdx.x]) atomicAdd(&hist[threadIdx.x], lh[threadIdx.x]);
}

// K2: serial prefix over 64 bins
__global__ void k_prefix(const int* __restrict__ hist, int* __restrict__ offsets) {
  if (threadIdx.x == 0) {
    int r = 0;
    for (int c = 0; c < 64; ++c) { offsets[c] = r; r += hist[c]; }
    offsets[64] = r;
  }
}

// K3: two-level scatter into cell buckets
__global__ void k_scatter(const float* __restrict__ attr, const int* __restrict__ offsets,
                          int* __restrict__ cursors, int* __restrict__ sorted) {
  __shared__ int lcnt[64], lbase[64], lcur[64];
  int tid = threadIdx.x;
  if (tid < 64) { lcnt[tid] = 0; lcur[tid] = 0; }
  __syncthreads();
  int per = (EE + gridDim.x - 1) / gridDim.x;
  int b0 = blockIdx.x * per;
  int b1 = min(b0 + per, EE);
  for (int e = b0 + tid; e < b1; e += blockDim.x) {
    int l0, l1, l2; float f0, f1, f2;
    cell_of(attr[e*3], attr[e*3+1], attr[e*3+2], l0, l1, l2, f0, f1, f2);
    atomicAdd(&lcnt[l0 | (l1 << 2) | (l2 << 4)], 1);
  }
  __syncthreads();
  if (tid < 64 && lcnt[tid]) lbase[tid] = offsets[tid] + atomicAdd(&cursors[tid], lcnt[tid]);
  __syncthreads();
  for (int e = b0 + tid; e < b1; e += blockDim.x) {
    int l0, l1, l2; float f0, f1, f2;
    cell_of(attr[e*3], attr[e*3+1], attr[e*3+2], l0, l1, l2, f0, f1, f2);
    int c = l0 | (l1 << 2) | (l2 << 4);
    int p = atomicAdd(&lcur[c], 1);
    sorted[lbase[c] + p] = e;
  }
}

// K4: main edge kernel. Wave = 64 lanes; lane = (o in 0..31, half hh in 0..1).
// Outer loop over cell-runs; W held in 4x ext_vector<16> = 64 VGPRs.
// __launch_bounds__(256, 2): relax occupancy target so the allocator has a
// 256-VGPR budget (default target squeezed to 48 VGPR by re-loading W per
// edge -> L1-bound, 143us). The "+v" asm makes W asm-defined: the compiler
// cannot rematerialize it by re-loading from global -- register or scratch
// are the only options, and the budget slack makes it pick registers.
__global__ __launch_bounds__(256, 2) void k_edge(
    const float* __restrict__ x, const int* __restrict__ esrc, const int* __restrict__ edst,
    const float* __restrict__ attr, const float* __restrict__ weight,
    const int* __restrict__ sorted, const int* __restrict__ offsets,
    float* __restrict__ agg, int nwaves) {
  int gwave = (blockIdx.x * blockDim.x + threadIdx.x) >> 6;
  int lane = threadIdx.x & 63;
  int o = lane & 31;
  int hh = lane >> 5;
  int per = (EE + nwaves - 1) / nwaves;
  int p0 = gwave * per;
  int p1 = min(p0 + per, EE);

  f16v W0, W1, W2, W3;

#define LOADW(Wv, S4) do {                                                    \
    int c_ = hh * 4 + (S4);                                                   \
    int wi_ = (c0 + (c_ & 1)) + 5 * (c1 + ((c_ >> 1) & 1)) + 25 * (c2 + (c_ >> 2)); \
    const float* wp_ = weight + wi_ * (CIN * COUT) + o;                       \
    _Pragma("unroll")                                                         \
    for (int i_ = 0; i_ < 16; ++i_) Wv[i_] = wp_[i_ * 32];                    \
  } while (0)

  int p = p0;
  while (p < p1) {
    // determine current cell from first edge of the run
    int e0 = __builtin_amdgcn_readfirstlane(sorted[p]);
    int l0, l1, l2; float t0, t1, t2;
    cell_of(attr[e0*3], attr[e0*3+1], attr[e0*3+2], l0, l1, l2, t0, t1, t2);
    int cell = __builtin_amdgcn_readfirstlane(l0 | (l1 << 2) | (l2 << 4));
    int c0 = cell & 3, c1 = (cell >> 2) & 3, c2 = cell >> 4;
    LOADW(W0, 0); LOADW(W1, 1); LOADW(W2, 2); LOADW(W3, 3);
    // Opaque the W values: no rematerialization-by-reload possible past here.
    asm volatile("" : "+v"(W0), "+v"(W1), "+v"(W2), "+v"(W3));
    int pe = min(p1, offsets[cell + 1]);

    for (; p < pe; ++p) {
      int e = __builtin_amdgcn_readfirstlane(sorted[p]);
      float v0 = attr[e*3] * 4.0f, v1 = attr[e*3+1] * 4.0f, v2 = attr[e*3+2] * 4.0f;
      float f0 = v0 - (float)c0, f1 = v1 - (float)c1, f2 = v2 - (float)c2;
      int src = __builtin_amdgcn_readfirstlane(esrc[e]);
      int dst = __builtin_amdgcn_readfirstlane(edst[e]);
      const float* xp = x + src * CIN;
      float m0 = 0.0f, m1 = 0.0f, m2 = 0.0f, m3 = 0.0f;
#pragma unroll
      for (int i = 0; i < CIN; ++i) {
        float xi = xp[i];
        m0 = fmaf(xi, W0[i], m0);
        m1 = fmaf(xi, W1[i], m1);
        m2 = fmaf(xi, W2[i], m2);
        m3 = fmaf(xi, W3[i], m3);
      }
      float g0 = 1.0f - f0, g1 = 1.0f - f1;
      float bz = hh ? f2 : 1.0f - f2;
      float acc = (g0 * g1) * m0;
      acc = fmaf(f0 * g1, m1, acc);
      acc = fmaf(g0 * f1, m2, acc);
      acc = fmaf(f0 * f1, m3, acc);
      acc *= bz;
      acc += __shfl_xor(acc, 32);
      if (hh == 0) atomicAdd(&agg[dst * COUT + o], acc);
    }
  }
#undef LOADW
}

// K5: node kernel: mean-agg + x@root + bias, ELU, write h to out, BN partial sums
__global__ __launch_bounds__(1024) void k_node(
    const float* __restrict__ x, const float* __restrict__ agg, const int* __restrict__ degi,
    const float* __restrict__ root, const float* __restrict__ bias,
    float* __restrict__ hout, float* __restrict__ gsum, float* __restrict__ gsumsq) {
  __shared__ float sred[2][16][32];
  int tid = threadIdx.x;
  int o = tid & 31;
  int nl = tid >> 5;                 // node within block, 0..31
  int n = blockIdx.x * 32 + nl;
  float s1 = 0.0f, s2 = 0.0f;
  if (n < NN) {
    float a = agg[n * COUT + o] / fmaxf((float)degi[n], 1.0f);
    const float* xp = x + n * CIN;
    float r = 0.0f;
#pragma unroll
    for (int i = 0; i < CIN; ++i) r = fmaf(xp[i], root[i * COUT + o], r);
    float hv = a + r + bias[o];
    hv = hv > 0.0f ? hv : expm1f(hv);
    hout[n * COUT + o] = hv;
    s1 = hv; s2 = hv * hv;
  }
  s1 += __shfl_xor(s1, 32);
  s2 += __shfl_xor(s2, 32);
  int w = tid >> 6;                  // wave 0..15
  if ((tid & 63) < 32) { sred[0][w][o] = s1; sred[1][w][o] = s2; }
  __syncthreads();
  if (tid < 32) {
    float t1 = 0.0f, t2 = 0.0f;
#pragma unroll
    for (int w2 = 0; w2 < 16; ++w2) { t1 += sred[0][w2][o]; t2 += sred[1][w2][o]; }
    atomicAdd(&gsum[o], t1);
    atomicAdd(&gsumsq[o], t2);
  }
}

// K6: finalize BatchNorm in-place on out
__global__ void k_bn(float* __restrict__ out, const float* __restrict__ gsum,
                     const float* __restrict__ gsumsq, const float* __restrict__ gamma,
                     const float* __restrict__ beta) {
  int idx = blockIdx.x * blockDim.x + threadIdx.x;
  if (idx >= NN * COUT) return;
  int o = idx & 31;
  float m = gsum[o] * (1.0f / NN);
  float var = gsumsq[o] * (1.0f / NN) - m * m;
  float inv = rsqrtf(var + 1e-5f);
  out[idx] = (out[idx] - m) * inv * gamma[o] + beta[o];
}

extern "C" void kernel_launch(void* const* d_in, const int* in_sizes, int n_in,
                              void* d_out, int out_size, void* d_ws, size_t ws_size,
                              hipStream_t stream) {
  const float* x      = (const float*)d_in[0];
  const int*   ei     = (const int*)d_in[1];
  const float* attr   = (const float*)d_in[2];
  const float* weight = (const float*)d_in[3];
  const float* root   = (const float*)d_in[4];
  const float* bias   = (const float*)d_in[5];
  const float* gamma  = (const float*)d_in[6];
  const float* beta   = (const float*)d_in[7];
  float* out = (float*)d_out;
  char* ws = (char*)d_ws;

  float* agg     = (float*)(ws + OFF_AGG);
  int*   degi    = (int*)(ws + OFF_DEG);
  int*   hist    = (int*)(ws + OFF_HIST);
  int*   cursors = (int*)(ws + OFF_CUR);
  float* gsum    = (float*)(ws + OFF_SUM);
  float* gsumsq  = (float*)(ws + OFF_SUMSQ);
  int*   offsets = (int*)(ws + OFF_OFFS);
  int*   sorted  = (int*)(ws + OFF_SORT);
  const int* esrc = ei;
  const int* edst = ei + EE;

  hipMemsetAsync(ws, 0, ZERO_BYTES, stream);
  k_hist<<<512, 256, 0, stream>>>(attr, edst, hist, degi);
  k_prefix<<<1, 64, 0, stream>>>(hist, offsets);
  k_scatter<<<512, 256, 0, stream>>>(attr, offsets, cursors, sorted);
  const int NB4 = 1024;  // 4096 waves
  k_edge<<<NB4, 256, 0, stream>>>(x, esrc, edst, attr, weight, sorted, offsets, agg, NB4 * 4);
  k_node<<<(NN + 31) / 32, 1024, 0, stream>>>(x, agg, degi, root, bias, out, gsum, gsumsq);
  k_bn<<<(NN * COUT) / 256, 256, 0, stream>>>(out, gsum, gsumsq, gamma, beta);
}

// Round 4
// 133.287 us; speedup vs baseline: 1.9700x; 1.6534x over previous
//
#include <hip/hip_runtime.h>

#define NN 50000
#define EE 400000
#define CIN 16
#define COUT 32
#define NTILES (EE / 32)

// ---- workspace layout (bytes) ---- (identical to R1-R3: known to fit ws)
#define OFF_AGG   0                        // float agg[NN*COUT]
#define OFF_DEG   (NN*COUT*4)              // int   degi[NN]
#define OFF_HIST  (OFF_DEG + NN*4)         // int   hist[64]
#define OFF_CUR   (OFF_HIST + 256)         // int   cursors[64]
#define OFF_SUM   (OFF_CUR + 256)          // float gsum[32]
#define OFF_SUMSQ (OFF_SUM + 128)          // float gsumsq[32]
#define ZERO_BYTES (OFF_SUMSQ + 128)
#define OFF_OFFS  ZERO_BYTES               // int offsets[65] (pad 512)
#define OFF_SORT  (OFF_OFFS + 512)         // int sorted[EE]

typedef float f32x4  __attribute__((ext_vector_type(4)));
typedef float f32x16 __attribute__((ext_vector_type(16)));
typedef short short8 __attribute__((ext_vector_type(8)));

__device__ __forceinline__ void cell_of(float a0, float a1, float a2,
                                        int& l0, int& l1, int& l2,
                                        float& f0, float& f1, float& f2) {
  float v0 = a0 * 4.0f, v1 = a1 * 4.0f, v2 = a2 * 4.0f;
  l0 = min(max((int)v0, 0), 3);
  l1 = min(max((int)v1, 0), 3);
  l2 = min(max((int)v2, 0), 3);
  f0 = v0 - (float)l0; f1 = v1 - (float)l1; f2 = v2 - (float)l2;
}

// K1: per-cell histogram + in-degree
__global__ void k_hist(const float* __restrict__ attr, const int* __restrict__ edst,
                       int* __restrict__ hist, int* __restrict__ degi) {
  __shared__ int lh[64];
  if (threadIdx.x < 64) lh[threadIdx.x] = 0;
  __syncthreads();
  for (int e = blockIdx.x * blockDim.x + threadIdx.x; e < EE; e += gridDim.x * blockDim.x) {
    int l0, l1, l2; float f0, f1, f2;
    cell_of(attr[e*3], attr[e*3+1], attr[e*3+2], l0, l1, l2, f0, f1, f2);
    atomicAdd(&lh[l0 | (l1 << 2) | (l2 << 4)], 1);
    atomicAdd(&degi[edst[e]], 1);
  }
  __syncthreads();
  if (threadIdx.x < 64 && lh[threadIdx.x]) atomicAdd(&hist[threadIdx.x], lh[threadIdx.x]);
}

// K2: serial prefix over 64 bins
__global__ void k_prefix(const int* __restrict__ hist, int* __restrict__ offsets) {
  if (threadIdx.x == 0) {
    int r = 0;
    for (int c = 0; c < 64; ++c) { offsets[c] = r; r += hist[c]; }
    offsets[64] = r;
  }
}

// K3: two-level scatter into cell buckets
__global__ void k_scatter(const float* __restrict__ attr, const int* __restrict__ offsets,
                          int* __restrict__ cursors, int* __restrict__ sorted) {
  __shared__ int lcnt[64], lbase[64], lcur[64];
  int tid = threadIdx.x;
  if (tid < 64) { lcnt[tid] = 0; lcur[tid] = 0; }
  __syncthreads();
  int per = (EE + gridDim.x - 1) / gridDim.x;
  int b0 = blockIdx.x * per;
  int b1 = min(b0 + per, EE);
  for (int e = b0 + tid; e < b1; e += blockDim.x) {
    int l0, l1, l2; float f0, f1, f2;
    cell_of(attr[e*3], attr[e*3+1], attr[e*3+2], l0, l1, l2, f0, f1, f2);
    atomicAdd(&lcnt[l0 | (l1 << 2) | (l2 << 4)], 1);
  }
  __syncthreads();
  if (tid < 64 && lcnt[tid]) lbase[tid] = offsets[tid] + atomicAdd(&cursors[tid], lcnt[tid]);
  __syncthreads();
  for (int e = b0 + tid; e < b1; e += blockDim.x) {
    int l0, l1, l2; float f0, f1, f2;
    cell_of(attr[e*3], attr[e*3+1], attr[e*3+2], l0, l1, l2, f0, f1, f2);
    int c = l0 | (l1 << 2) | (l2 << 4);
    int p = atomicAdd(&lcur[c], 1);
    sorted[lbase[c] + p] = e;
  }
}

// K4: MFMA edge kernel. One wave per 32-edge tile of the cell-sorted list.
// D[32 edges][32 outs] = sum over 8 combos: A_c[32x16] * B_c[16x32], bf16 MFMA.
// A-frag lane(row=lane&31, half=lane>>5): w_c[row] * xs[row][half*8+j], j=0..7.
// B-frag lane(col=lane&31, half): W[corner_c][half*8+j][col] (reloaded per tile
// from L1 -- 2 dwords/edge amortized; no register-residency gamble).
// Tiles straddling a cell boundary (~63/12500) run two masked passes; masked
// rows have A=0 so their atomicAdd contributes exact 0.
__global__ __launch_bounds__(256) void k_edge(
    const float* __restrict__ x, const int* __restrict__ esrc, const int* __restrict__ edst,
    const float* __restrict__ attr, const float* __restrict__ weight,
    const int* __restrict__ sorted, float* __restrict__ agg) {
  int gwave = (int)((blockIdx.x * blockDim.x + threadIdx.x) >> 6);
  if (gwave >= NTILES) return;
  int lane = threadIdx.x & 63;
  int col = lane & 31;          // A-row (edge slot), B-col, C-col
  int half = lane >> 5;

  int p = gwave * 32 + col;
  int e = sorted[p];
  float a0 = attr[e*3+0], a1 = attr[e*3+1], a2 = attr[e*3+2];
  int src = esrc[e];
  int dst = edst[e];

  float v0 = a0 * 4.0f, v1 = a1 * 4.0f, v2 = a2 * 4.0f;
  int l0 = min(max((int)v0, 0), 3);
  int l1 = min(max((int)v1, 0), 3);
  int l2 = min(max((int)v2, 0), 3);
  float f0 = v0 - (float)l0, f1 = v1 - (float)l1, f2 = v2 - (float)l2;
  int mycell = l0 | (l1 << 2) | (l2 << 4);

  const float* xp = x + src * CIN + half * 8;
  float xs[8];
  {
    f32x4 xa = *(const f32x4*)xp;
    f32x4 xb = *(const f32x4*)(xp + 4);
#pragma unroll
    for (int j = 0; j < 4; ++j) { xs[j] = xa[j]; xs[j + 4] = xb[j]; }
  }

  int c_first = __builtin_amdgcn_readfirstlane(mycell);
  int c_last  = __builtin_amdgcn_readfirstlane(__shfl(mycell, 31, 64));
  int npass = (c_first == c_last) ? 1 : 2;

  f32x16 acc;
#pragma unroll
  for (int r = 0; r < 16; ++r) acc[r] = 0.0f;

  float g0 = 1.0f - f0, g1 = 1.0f - f1, g2 = 1.0f - f2;

  for (int pass = 0; pass < npass; ++pass) {
    int cell = pass ? c_last : c_first;
    int c0 = cell & 3, c1 = (cell >> 2) & 3, c2 = cell >> 4;
    bool act = (mycell == cell);
#pragma unroll
    for (int cb = 0; cb < 8; ++cb) {
      float w = ((cb & 1) ? f0 : g0) * (((cb >> 1) & 1) ? f1 : g1) * (((cb >> 2) & 1) ? f2 : g2);
      w = act ? w : 0.0f;
      short8 av;
#pragma unroll
      for (int j = 0; j < 8; ++j)
        av[j] = __builtin_bit_cast(short, (__bf16)(w * xs[j]));
      int wi = (c0 + (cb & 1)) + 5 * (c1 + ((cb >> 1) & 1)) + 25 * (c2 + (cb >> 2));
      const float* wp = weight + wi * (CIN * COUT) + (half * 8) * COUT + col;
      short8 bv;
#pragma unroll
      for (int j = 0; j < 8; ++j)
        bv[j] = __builtin_bit_cast(short, (__bf16)wp[j * COUT]);
      acc = __builtin_amdgcn_mfma_f32_32x32x16_bf16(av, bv, acc, 0, 0, 0);
    }
  }

  // C/D layout (HW-verified): col=lane&31, row=(r&3)+8*(r>>2)+4*half
#pragma unroll
  for (int r = 0; r < 16; ++r) {
    int orow = (r & 3) + 8 * (r >> 2) + 4 * half;
    int d = __shfl(dst, orow, 64);
    atomicAdd(&agg[d * COUT + col], acc[r]);
  }
}

// K5: node kernel: mean-agg + x@root + bias, ELU, write h to out, BN partial sums
__global__ __launch_bounds__(1024) void k_node(
    const float* __restrict__ x, const float* __restrict__ agg, const int* __restrict__ degi,
    const float* __restrict__ root, const float* __restrict__ bias,
    float* __restrict__ hout, float* __restrict__ gsum, float* __restrict__ gsumsq) {
  __shared__ float sred[2][16][32];
  int tid = threadIdx.x;
  int o = tid & 31;
  int nl = tid >> 5;                 // node within block, 0..31
  int n = blockIdx.x * 32 + nl;
  float s1 = 0.0f, s2 = 0.0f;
  if (n < NN) {
    float a = agg[n * COUT + o] / fmaxf((float)degi[n], 1.0f);
    const float* xp = x + n * CIN;
    float r = 0.0f;
#pragma unroll
    for (int i = 0; i < CIN; ++i) r = fmaf(xp[i], root[i * COUT + o], r);
    float hv = a + r + bias[o];
    hv = hv > 0.0f ? hv : expm1f(hv);
    hout[n * COUT + o] = hv;
    s1 = hv; s2 = hv * hv;
  }
  s1 += __shfl_xor(s1, 32);
  s2 += __shfl_xor(s2, 32);
  int w = tid >> 6;                  // wave 0..15
  if ((tid & 63) < 32) { sred[0][w][o] = s1; sred[1][w][o] = s2; }
  __syncthreads();
  if (tid < 32) {
    float t1 = 0.0f, t2 = 0.0f;
#pragma unroll
    for (int w2 = 0; w2 < 16; ++w2) { t1 += sred[0][w2][o]; t2 += sred[1][w2][o]; }
    atomicAdd(&gsum[o], t1);
    atomicAdd(&gsumsq[o], t2);
  }
}

// K6: finalize BatchNorm in-place on out
__global__ void k_bn(float* __restrict__ out, const float* __restrict__ gsum,
                     const float* __restrict__ gsumsq, const float* __restrict__ gamma,
                     const float* __restrict__ beta) {
  int idx = blockIdx.x * blockDim.x + threadIdx.x;
  if (idx >= NN * COUT) return;
  int o = idx & 31;
  float m = gsum[o] * (1.0f / NN);
  float var = gsumsq[o] * (1.0f / NN) - m * m;
  float inv = rsqrtf(var + 1e-5f);
  out[idx] = (out[idx] - m) * inv * gamma[o] + beta[o];
}

extern "C" void kernel_launch(void* const* d_in, const int* in_sizes, int n_in,
                              void* d_out, int out_size, void* d_ws, size_t ws_size,
                              hipStream_t stream) {
  const float* x      = (const float*)d_in[0];
  const int*   ei     = (const int*)d_in[1];
  const float* attr   = (const float*)d_in[2];
  const float* weight = (const float*)d_in[3];
  const float* root   = (const float*)d_in[4];
  const float* bias   = (const float*)d_in[5];
  const float* gamma  = (const float*)d_in[6];
  const float* beta   = (const float*)d_in[7];
  float* out = (float*)d_out;
  char* ws = (char*)d_ws;

  float* agg     = (float*)(ws + OFF_AGG);
  int*   degi    = (int*)(ws + OFF_DEG);
  int*   hist    = (int*)(ws + OFF_HIST);
  int*   cursors = (int*)(ws + OFF_CUR);
  float* gsum    = (float*)(ws + OFF_SUM);
  float* gsumsq  = (float*)(ws + OFF_SUMSQ);
  int*   offsets = (int*)(ws + OFF_OFFS);
  int*   sorted  = (int*)(ws + OFF_SORT);
  const int* esrc = ei;
  const int* edst = ei + EE;

  hipMemsetAsync(ws, 0, ZERO_BYTES, stream);
  k_hist<<<512, 256, 0, stream>>>(attr, edst, hist, degi);
  k_prefix<<<1, 64, 0, stream>>>(hist, offsets);
  k_scatter<<<512, 256, 0, stream>>>(attr, offsets, cursors, sorted);
  // one wave per 32-edge tile: 12500 waves = 3125 blocks of 256
  k_edge<<<NTILES / 4, 256, 0, stream>>>(x, esrc, edst, attr, weight, sorted, agg);
  k_node<<<(NN + 31) / 32, 1024, 0, stream>>>(x, agg, degi, root, bias, out, gsum, gsumsq);
  k_bn<<<(NN * COUT) / 256, 256, 0, stream>>>(out, gsum, gsumsq, gamma, beta);
}